// Round 11
// baseline (53.104 us; speedup 1.0000x reference)
//
#include <hip/hip_runtime.h>
#include <hip/hip_bf16.h>

// MMD via symmetric triangular chunk decomposition, half-tile grid.
// u = [x; w] (16384 pts), s = [-1; +1]:
//   result = (sum_{i,j} s_i s_j k(u_i,u_j)) / 8192^2,   k = exp(-d2/2) = 2^(CEXP*d2)
// 64 chunks of 256 points; 2080 (I>=J) tiles split into 4160 half-tile blocks.
// Off-diagonal tiles weighted x2 (symmetry); diagonal x1.
//
// R11 = R7 (proven absmax 0.0, 30.5 us) + __launch_bounds__(256, 8).
// Evidence: R7-structure VGPR = 40 (counters) << 64-VGPR budget at 8 waves/EU,
// so R4's failure mode (48->32 squeeze, spills) does not apply. R9 counters
// showed Occ 46% / VALUBusy 71% under (,6): residency cap binding, VALU idle.
// 8 blocks/CU raises the cap to 32 waves/CU.
//
// Numeric-path ledger (10 rounds of evidence):
//   PASS: v_exp_f32 via builtin (R1-R3, R7); poly via libm ldexp (R6, R9).
//   FAIL: bit-punned exponent tricks (R5: 1.6e-3, R8: 2.7e-5) and hand
//         v_pk_* asm (R10: 1.7e-4). Builtins/libm semantics only -- no
//         bit-casting, no packed-f32 inline asm.
// k = 2^arg * E_B with arg = fma(ax',bx, fma(ay',by, fma(az',bz, a2c))),
// E_B = 2^(CEXP*|b|^2) staged in LDS; accumulate pkfma(ev, E_B, acc).

#define NPTS     8192
#define CH       256
#define NC       64                 // 16384 / CH
#define NXC      32                 // chunks holding x (first half)
#define NB_TILES 2080               // NC*(NC+1)/2
#define NB_UNITS 4160               // 2 half-tiles per tile
#define BLOCK    256
#define CEXP     (-0.72134752044448169f)     // -1/(2 ln 2)
#define M2CEXP   (1.44269504088896340736f)   // -2*CEXP = 1/ln2

typedef float f32x2 __attribute__((ext_vector_type(2)));
typedef float f32x4 __attribute__((ext_vector_type(4)));

__device__ __forceinline__ f32x2 pkfma(f32x2 a, f32x2 b, f32x2 c) {
#if __has_builtin(__builtin_elementwise_fma)
    return __builtin_elementwise_fma(a, b, c);
#else
    f32x2 r; r.x = fmaf(a.x, b.x, c.x); r.y = fmaf(a.y, b.y, c.y); return r;
#endif
}

// Single-instruction 2^x (R3/R7-proven).
__device__ __forceinline__ float fexp2(float v) {
#if __has_builtin(__builtin_amdgcn_exp2f)
    return __builtin_amdgcn_exp2f(v);
#else
    float r;
    asm("v_exp_f32 %0, %1" : "=v"(r) : "v"(v));
    return r;
#endif
}

#define PK2(v) ((f32x2){(v), (v)})

__global__ __launch_bounds__(BLOCK, 8) void mmd_tri(const float* __restrict__ x,
                                                    const float* __restrict__ w,
                                                    float* __restrict__ partials) {
    __shared__ f32x4  sAX[CH/4], sAY[CH/4], sAZ[CH/4], sA2[CH/4];  // A-form SoA
    __shared__ float4 sB[CH];                  // (bx, by, bz, E_B=2^(C|b|^2))
    __shared__ float  red[4];

    const int unit = blockIdx.x;
    const int tile = unit >> 1;                // triangular tile index
    const int half = unit & 1;                 // a-rows [half*128, half*128+128)

    // tile -> lower-triangle chunk pair (I, J), J <= I
    int I = (int)((sqrtf(8.0f * (float)tile + 1.0f) - 1.0f) * 0.5f);
    while ((I + 1) * (I + 2) / 2 <= tile) ++I;
    while (I * (I + 1) / 2 > tile) --I;
    const int J = tile - I * (I + 1) / 2;

    const int tid = threadIdx.x;
    {
        int gi = I * CH + tid;                      // chunks never straddle x/w
        const float* s = (gi < NPTS) ? x : w;
        int ii = gi & (NPTS - 1);
        float px = s[3*ii], py = s[3*ii+1], pz = s[3*ii+2];
        ((float*)sAX)[tid] = M2CEXP * px;
        ((float*)sAY)[tid] = M2CEXP * py;
        ((float*)sAZ)[tid] = M2CEXP * pz;
        ((float*)sA2)[tid] = CEXP * (px*px + py*py + pz*pz);

        int gj = J * CH + tid;
        const float* t = (gj < NPTS) ? x : w;
        int jj = gj & (NPTS - 1);
        float qx = t[3*jj], qy = t[3*jj+1], qz = t[3*jj+2];
        sB[tid] = make_float4(qx, qy, qz,
                              fexp2(CEXP * (qx*qx + qy*qy + qz*qz)));
    }
    __syncthreads();

    const int lane = tid & 63;
    const int wave = tid >> 6;

    f32x2 acc2[4];
#pragma unroll
    for (int p = 0; p < 4; ++p) acc2[p] = PK2(0.0f);

#pragma unroll 1
    for (int ai = half * 4; ai < half * 4 + 4; ++ai) {  // 4 a-iters (half tile)
        const int a4 = (ai * 32 + wave * 8) >> 2;   // index into f32x4 SoA
        f32x4 ax0 = sAX[a4], ax1 = sAX[a4 + 1];
        f32x4 ay0 = sAY[a4], ay1 = sAY[a4 + 1];
        f32x4 az0 = sAZ[a4], az1 = sAZ[a4 + 1];
        f32x4 a20 = sA2[a4], a21 = sA2[a4 + 1];
        // q-pairs as even-aligned subregisters of the x4 loads (no movs)
        f32x2 axp[4] = { ax0.xy, ax0.zw, ax1.xy, ax1.zw };
        f32x2 ayp[4] = { ay0.xy, ay0.zw, ay1.xy, ay1.zw };
        f32x2 azp[4] = { az0.xy, az0.zw, az1.xy, az1.zw };
        f32x2 a2p[4] = { a20.xy, a20.zw, a21.xy, a21.zw };

#pragma unroll
        for (int k = 0; k < CH / 64; ++k) {         // each lane: 1 b-point per k
            float4 b = sB[k * 64 + lane];           // one ds_read_b128 / 512 pairs
            f32x2 bxx = PK2(b.x);
            f32x2 byy = PK2(b.y);
            f32x2 bzz = PK2(b.z);
            f32x2 ebw = PK2(b.w);
#pragma unroll
            for (int p = 0; p < 4; ++p) {
                f32x2 arg = pkfma(axp[p], bxx,
                            pkfma(ayp[p], byy,
                            pkfma(azp[p], bzz, a2p[p])));
                f32x2 ev;
                ev.x = fexp2(arg.x);
                ev.y = fexp2(arg.y);
                acc2[p] = pkfma(ev, ebw, acc2[p]);  // k = 2^arg * E_B, folded
            }
        }
    }

    float tot = 0.0f;
#pragma unroll
    for (int p = 0; p < 4; ++p) tot += acc2[p].x + acc2[p].y;
#pragma unroll
    for (int off = 32; off > 0; off >>= 1)
        tot += __shfl_xor(tot, off, 64);

    if (lane == 0) red[wave] = tot;
    __syncthreads();
    if (tid == 0) {
        const float sa = (I < NXC) ? -1.0f : 1.0f;
        const float sb = (J < NXC) ? -1.0f : 1.0f;
        const float wt = (I == J) ? 1.0f : 2.0f;
        partials[unit] = (sa * sb * wt) * ((red[0] + red[1]) + (red[2] + red[3]));
    }
}

__global__ __launch_bounds__(256) void mmd_reduce(const float* __restrict__ partials,
                                                  float* __restrict__ out) {
    __shared__ float red[4];
    const int tid = threadIdx.x;
    float v = 0.0f;
    for (int i = tid; i < NB_UNITS; i += 256) v += partials[i];
#pragma unroll
    for (int off = 32; off > 0; off >>= 1)
        v += __shfl_xor(v, off, 64);
    if ((tid & 63) == 0) red[tid >> 6] = v;
    __syncthreads();
    if (tid == 0)
        out[0] = ((red[0] + red[1]) + (red[2] + red[3])) * (1.0f / 67108864.0f);
}

extern "C" void kernel_launch(void* const* d_in, const int* in_sizes, int n_in,
                              void* d_out, int out_size, void* d_ws, size_t ws_size,
                              hipStream_t stream) {
    const float* x = (const float*)d_in[0];
    const float* w = (const float*)d_in[1];
    float* out      = (float*)d_out;
    float* partials = (float*)d_ws;   // NB_UNITS floats = 16640 B

    hipLaunchKernelGGL(mmd_tri, dim3(NB_UNITS), dim3(BLOCK), 0, stream, x, w, partials);
    hipLaunchKernelGGL(mmd_reduce, dim3(1), dim3(256), 0, stream, partials, out);
}

// Round 13
// 30.982 us; speedup vs baseline: 1.7140x; 1.7140x over previous
//
#include <hip/hip_runtime.h>
#include <hip/hip_bf16.h>

// MMD via symmetric triangular chunk decomposition, half-tile grid.
// u = [x; w] (16384 pts), s = [-1; +1]:
//   result = (sum_{i,j} s_i s_j k(u_i,u_j)) / 8192^2,   k = exp(-d2/2) = 2^(CEXP*d2)
// 64 chunks of 256 points; 2080 (I>=J) tiles split into 4160 half-tile blocks.
// Off-diagonal tiles weighted x2 (symmetry); diagonal x1.
//
// R13 = R7 (absmax 0.0, 30.5 us) with the ai-loop FULLY UNROLLED (was
// #pragma unroll 1). Rationale: VALUBusy 71-75% / Occ 46% -> ~25% issue-idle;
// the unroll-1 wall limited in-flight chain->exp->acc streams to 4; full
// unroll exposes all 16 per half-tile so the scheduler can fill trans-wait
// bubbles with the next section's fma/LDS work. Unrolling preserves each
// accumulator's FP order -> bit-identical to R7.
//
// Final numeric-path ledger (12 rounds):
//   PASS (6/6): v_exp_f32 builtin (R1-R3, R7); poly via libm ldexp (R6, R9).
//   FAIL (0/3): bit-punned exponent (R5 1.6e-3, R8 2.7e-5); VOP3P pk-f32 asm
//     (R12 1.3e-2, clean discriminator). Packed-f32 asm PERMANENTLY BANNED.
//   (256,8) launch bounds -> 32-VGPR budget -> spills (R4, R11). Keep (256,6).
//   E_A factoring -> 2^26-magnitude accumulators absorb O(1) terms (R10). Keep
//   normalized accumulation: ev*ebw <= 1 formed inside the fma.

#define NPTS     8192
#define CH       256
#define NC       64                 // 16384 / CH
#define NXC      32                 // chunks holding x (first half)
#define NB_TILES 2080               // NC*(NC+1)/2
#define NB_UNITS 4160               // 2 half-tiles per tile
#define BLOCK    256
#define CEXP     (-0.72134752044448169f)     // -1/(2 ln 2)
#define M2CEXP   (1.44269504088896340736f)   // -2*CEXP = 1/ln2

typedef float f32x2 __attribute__((ext_vector_type(2)));
typedef float f32x4 __attribute__((ext_vector_type(4)));

__device__ __forceinline__ f32x2 pkfma(f32x2 a, f32x2 b, f32x2 c) {
#if __has_builtin(__builtin_elementwise_fma)
    return __builtin_elementwise_fma(a, b, c);
#else
    f32x2 r; r.x = fmaf(a.x, b.x, c.x); r.y = fmaf(a.y, b.y, c.y); return r;
#endif
}

// Single-instruction 2^x (R3/R7-proven).
__device__ __forceinline__ float fexp2(float v) {
#if __has_builtin(__builtin_amdgcn_exp2f)
    return __builtin_amdgcn_exp2f(v);
#else
    float r;
    asm("v_exp_f32 %0, %1" : "=v"(r) : "v"(v));
    return r;
#endif
}

#define PK2(v) ((f32x2){(v), (v)})

__global__ __launch_bounds__(BLOCK, 6) void mmd_tri(const float* __restrict__ x,
                                                    const float* __restrict__ w,
                                                    float* __restrict__ partials) {
    __shared__ f32x4  sAX[CH/4], sAY[CH/4], sAZ[CH/4], sA2[CH/4];  // A-form SoA
    __shared__ float4 sB[CH];                  // (bx, by, bz, E_B=2^(C|b|^2))
    __shared__ float  red[4];

    const int unit = blockIdx.x;
    const int tile = unit >> 1;                // triangular tile index
    const int half = unit & 1;                 // a-rows [half*128, half*128+128)

    // tile -> lower-triangle chunk pair (I, J), J <= I
    int I = (int)((sqrtf(8.0f * (float)tile + 1.0f) - 1.0f) * 0.5f);
    while ((I + 1) * (I + 2) / 2 <= tile) ++I;
    while (I * (I + 1) / 2 > tile) --I;
    const int J = tile - I * (I + 1) / 2;

    const int tid = threadIdx.x;
    {
        int gi = I * CH + tid;                      // chunks never straddle x/w
        const float* s = (gi < NPTS) ? x : w;
        int ii = gi & (NPTS - 1);
        float px = s[3*ii], py = s[3*ii+1], pz = s[3*ii+2];
        ((float*)sAX)[tid] = M2CEXP * px;
        ((float*)sAY)[tid] = M2CEXP * py;
        ((float*)sAZ)[tid] = M2CEXP * pz;
        ((float*)sA2)[tid] = CEXP * (px*px + py*py + pz*pz);

        int gj = J * CH + tid;
        const float* t = (gj < NPTS) ? x : w;
        int jj = gj & (NPTS - 1);
        float qx = t[3*jj], qy = t[3*jj+1], qz = t[3*jj+2];
        sB[tid] = make_float4(qx, qy, qz,
                              fexp2(CEXP * (qx*qx + qy*qy + qz*qz)));
    }
    __syncthreads();

    const int lane = tid & 63;
    const int wave = tid >> 6;

    f32x2 acc2[4];
#pragma unroll
    for (int p = 0; p < 4; ++p) acc2[p] = PK2(0.0f);

#pragma unroll
    for (int u = 0; u < 4; ++u) {               // FULL unroll: 4 a-iters visible
        const int ai = half * 4 + u;
        const int a4 = (ai * 32 + wave * 8) >> 2;   // index into f32x4 SoA
        f32x4 ax0 = sAX[a4], ax1 = sAX[a4 + 1];
        f32x4 ay0 = sAY[a4], ay1 = sAY[a4 + 1];
        f32x4 az0 = sAZ[a4], az1 = sAZ[a4 + 1];
        f32x4 a20 = sA2[a4], a21 = sA2[a4 + 1];
        // q-pairs as even-aligned subregisters of the x4 loads (no movs)
        f32x2 axp[4] = { ax0.xy, ax0.zw, ax1.xy, ax1.zw };
        f32x2 ayp[4] = { ay0.xy, ay0.zw, ay1.xy, ay1.zw };
        f32x2 azp[4] = { az0.xy, az0.zw, az1.xy, az1.zw };
        f32x2 a2p[4] = { a20.xy, a20.zw, a21.xy, a21.zw };

#pragma unroll
        for (int k = 0; k < CH / 64; ++k) {         // each lane: 1 b-point per k
            float4 b = sB[k * 64 + lane];           // one ds_read_b128 / 512 pairs
            f32x2 bxx = PK2(b.x);
            f32x2 byy = PK2(b.y);
            f32x2 bzz = PK2(b.z);
            f32x2 ebw = PK2(b.w);
#pragma unroll
            for (int p = 0; p < 4; ++p) {
                f32x2 arg = pkfma(axp[p], bxx,
                            pkfma(ayp[p], byy,
                            pkfma(azp[p], bzz, a2p[p])));
                f32x2 ev;
                ev.x = fexp2(arg.x);
                ev.y = fexp2(arg.y);
                acc2[p] = pkfma(ev, ebw, acc2[p]);  // k = 2^arg * E_B, folded
            }
        }
    }

    float tot = 0.0f;
#pragma unroll
    for (int p = 0; p < 4; ++p) tot += acc2[p].x + acc2[p].y;
#pragma unroll
    for (int off = 32; off > 0; off >>= 1)
        tot += __shfl_xor(tot, off, 64);

    if (lane == 0) red[wave] = tot;
    __syncthreads();
    if (tid == 0) {
        const float sa = (I < NXC) ? -1.0f : 1.0f;
        const float sb = (J < NXC) ? -1.0f : 1.0f;
        const float wt = (I == J) ? 1.0f : 2.0f;
        partials[unit] = (sa * sb * wt) * ((red[0] + red[1]) + (red[2] + red[3]));
    }
}

__global__ __launch_bounds__(256) void mmd_reduce(const float* __restrict__ partials,
                                                  float* __restrict__ out) {
    __shared__ float red[4];
    const int tid = threadIdx.x;
    float v = 0.0f;
    for (int i = tid; i < NB_UNITS; i += 256) v += partials[i];
#pragma unroll
    for (int off = 32; off > 0; off >>= 1)
        v += __shfl_xor(v, off, 64);
    if ((tid & 63) == 0) red[tid >> 6] = v;
    __syncthreads();
    if (tid == 0)
        out[0] = ((red[0] + red[1]) + (red[2] + red[3])) * (1.0f / 67108864.0f);
}

extern "C" void kernel_launch(void* const* d_in, const int* in_sizes, int n_in,
                              void* d_out, int out_size, void* d_ws, size_t ws_size,
                              hipStream_t stream) {
    const float* x = (const float*)d_in[0];
    const float* w = (const float*)d_in[1];
    float* out      = (float*)d_out;
    float* partials = (float*)d_ws;   // NB_UNITS floats = 16640 B

    hipLaunchKernelGGL(mmd_tri, dim3(NB_UNITS), dim3(BLOCK), 0, stream, x, w, partials);
    hipLaunchKernelGGL(mmd_reduce, dim3(1), dim3(256), 0, stream, partials, out);
}